// Round 1
// baseline (904.234 us; speedup 1.0000x reference)
//
#include <hip/hip_runtime.h>

#define LATENT 64
#define N_USERS_C 100000

// Edge-parallel SpMM: Eout[row[e], :] += vals[e] * Ein[col[e], :]
// One wave (64 lanes) per edge; lane = dim. row/col/vals are wave-uniform
// broadcast loads; E accesses are coalesced 256B per wave.
__global__ void spmm_atomic(const int* __restrict__ row,
                            const int* __restrict__ col,
                            const float* __restrict__ vals,
                            const float* __restrict__ Ein,
                            float* __restrict__ Eout,
                            int nnz) {
    int t = blockIdx.x * blockDim.x + threadIdx.x;
    int e = t >> 6;
    if (e >= nnz) return;
    int d = t & 63;
    int r = row[e];
    int c = col[e];
    float v = vals[e];
    atomicAdd(&Eout[r * LATENT + d], v * Ein[c * LATENT + d]);
}

// Accumulate E_k at the 3*batch gathered rows into acc (3*batch*64 floats).
__global__ void gather_acc(const int* __restrict__ users,
                           const int* __restrict__ pos,
                           const int* __restrict__ neg,
                           const float* __restrict__ E,
                           float* __restrict__ acc,
                           int batch) {
    int t = blockIdx.x * blockDim.x + threadIdx.x;
    int total = 3 * batch * LATENT;
    if (t >= total) return;
    int d = t & 63;
    int b = t >> 6;
    int g = b / batch;          // 0=user, 1=pos, 2=neg
    int bb = b - g * batch;
    int r = (g == 0) ? users[bb]
          : (g == 1) ? (N_USERS_C + pos[bb])
                     : (N_USERS_C + neg[bb]);
    acc[t] += E[r * LATENT + d];
}

// out layout: [u_emb, pos_emb, neg_emb, u_emb0, pos_emb0, neg_emb0], each batch*64.
// final_emb[r] = (E0[r] + E1[r] + E2[r] + E3[r]) / 4 ; acc holds E1+E2+E3 at gathered rows.
__global__ void finalize(const int* __restrict__ users,
                         const int* __restrict__ pos,
                         const int* __restrict__ neg,
                         const float* __restrict__ E0,
                         const float* __restrict__ acc,
                         float* __restrict__ out,
                         int batch) {
    int t = blockIdx.x * blockDim.x + threadIdx.x;
    int total = 3 * batch * LATENT;
    if (t >= total) return;
    int d = t & 63;
    int b = t >> 6;
    int g = b / batch;
    int bb = b - g * batch;
    int r = (g == 0) ? users[bb]
          : (g == 1) ? (N_USERS_C + pos[bb])
                     : (N_USERS_C + neg[bb]);
    float e0 = E0[r * LATENT + d];
    out[t] = 0.25f * (e0 + acc[t]);
    out[total + t] = e0;        // raw E0 gathers (outputs 3..5)
}

extern "C" void kernel_launch(void* const* d_in, const int* in_sizes, int n_in,
                              void* d_out, int out_size, void* d_ws, size_t ws_size,
                              hipStream_t stream) {
    const int*   users = (const int*)d_in[0];
    const int*   pos   = (const int*)d_in[1];
    const int*   neg   = (const int*)d_in[2];
    const float* E0    = (const float*)d_in[3];
    const int*   row   = (const int*)d_in[4];
    const int*   col   = (const int*)d_in[5];
    const float* vals  = (const float*)d_in[6];
    float*       out   = (float*)d_out;

    const int batch  = in_sizes[0];          // 4096
    const int nnz    = in_sizes[4];          // 1,200,000
    const int ntotal = in_sizes[3] / LATENT; // 150,000

    const size_t bufBytes = (size_t)ntotal * LATENT * sizeof(float); // 38.4 MB
    const size_t accBytes = (size_t)3 * batch * LATENT * sizeof(float);
    float* bufA = (float*)d_ws;
    float* bufB = (float*)((char*)d_ws + bufBytes);
    float* acc  = (float*)((char*)d_ws + 2 * bufBytes);

    // Zero both ping-pong buffers + acc (ws is poisoned 0xAA before every call).
    hipMemsetAsync(d_ws, 0, 2 * bufBytes + accBytes, stream);

    const int threads = 256;
    const int spmmBlocks = (int)(((long long)nnz * LATENT + threads - 1) / threads);
    const int gBlocks = (3 * batch * LATENT + threads - 1) / threads;

    // Layer 1: E1 = A @ E0  -> bufB
    spmm_atomic<<<spmmBlocks, threads, 0, stream>>>(row, col, vals, E0, bufB, nnz);
    gather_acc<<<gBlocks, threads, 0, stream>>>(users, pos, neg, bufB, acc, batch);

    // Layer 2: E2 = A @ E1  -> bufA
    spmm_atomic<<<spmmBlocks, threads, 0, stream>>>(row, col, vals, bufB, bufA, nnz);
    gather_acc<<<gBlocks, threads, 0, stream>>>(users, pos, neg, bufA, acc, batch);

    // Layer 3: E3 = A @ E2  -> bufB (re-zero first; stream order guards the read)
    hipMemsetAsync(bufB, 0, bufBytes, stream);
    spmm_atomic<<<spmmBlocks, threads, 0, stream>>>(row, col, vals, bufA, bufB, nnz);
    gather_acc<<<gBlocks, threads, 0, stream>>>(users, pos, neg, bufB, acc, batch);

    finalize<<<gBlocks, threads, 0, stream>>>(users, pos, neg, E0, acc, out, batch);
}

// Round 2
// 835.947 us; speedup vs baseline: 1.0817x; 1.0817x over previous
//
#include <hip/hip_runtime.h>

#define LATENT 64
#define N_USERS_C 100000

// ---------- CSR build ----------

__global__ void hist_kernel(const int* __restrict__ row, int* __restrict__ deg, int nnz) {
    int e = blockIdx.x * blockDim.x + threadIdx.x;
    if (e >= nnz) return;
    atomicAdd(&deg[row[e]], 1);
}

// Single-block exclusive scan: start[0]=0, start[i+1]=sum(deg[0..i]).
__global__ void exscan_kernel(const int* __restrict__ deg, int* __restrict__ start, int n) {
    __shared__ int part[1024];
    int t = threadIdx.x;
    int chunk = (n + 1023) >> 10;
    int lo = t * chunk;
    int hi = lo + chunk; if (hi > n) hi = n;
    int s = 0;
    for (int i = lo; i < hi; i++) s += deg[i];
    part[t] = s;
    __syncthreads();
    for (int off = 1; off < 1024; off <<= 1) {
        int v = (t >= off) ? part[t - off] : 0;
        __syncthreads();
        part[t] += v;
        __syncthreads();
    }
    int run = (t == 0) ? 0 : part[t - 1];
    if (t == 0) start[0] = 0;
    for (int i = lo; i < hi; i++) { run += deg[i]; start[i + 1] = run; }
}

// Scatter edges into CSR order; cursor pre-initialized to start[0..n).
__global__ void scatter_kernel(const int* __restrict__ row, const int* __restrict__ col,
                               const float* __restrict__ vals, int* __restrict__ cursor,
                               int2* __restrict__ edges, int nnz) {
    int e = blockIdx.x * blockDim.x + threadIdx.x;
    if (e >= nnz) return;
    int r = row[e];
    int p = atomicAdd(&cursor[r], 1);
    edges[p] = make_int2(col[e], __float_as_int(vals[e]));
}

// ---------- Row-parallel SpMM: one wave per row, lane = dim ----------

__global__ void spmm_csr(const int* __restrict__ start, const int2* __restrict__ edges,
                         const float* __restrict__ Ein, float* __restrict__ Eout,
                         int nrows) {
    int t = blockIdx.x * blockDim.x + threadIdx.x;
    int r = t >> 6;
    if (r >= nrows) return;
    int d = t & 63;
    int b = start[r];
    int e = start[r + 1];
    float acc = 0.0f;
    for (int k = b; k < e; k++) {
        int2 ed = edges[k];              // wave-uniform 8B load, one line per iter
        acc += __int_as_float(ed.y) * Ein[ed.x * LATENT + d];  // coalesced 256B gather
    }
    Eout[r * LATENT + d] = acc;
}

// ---------- epilogue (unchanged from R0) ----------

__global__ void gather_acc(const int* __restrict__ users, const int* __restrict__ pos,
                           const int* __restrict__ neg, const float* __restrict__ E,
                           float* __restrict__ acc, int batch) {
    int t = blockIdx.x * blockDim.x + threadIdx.x;
    int total = 3 * batch * LATENT;
    if (t >= total) return;
    int d = t & 63;
    int b = t >> 6;
    int g = b / batch;
    int bb = b - g * batch;
    int r = (g == 0) ? users[bb] : (g == 1) ? (N_USERS_C + pos[bb]) : (N_USERS_C + neg[bb]);
    acc[t] += E[r * LATENT + d];
}

__global__ void finalize(const int* __restrict__ users, const int* __restrict__ pos,
                         const int* __restrict__ neg, const float* __restrict__ E0,
                         const float* __restrict__ acc, float* __restrict__ out, int batch) {
    int t = blockIdx.x * blockDim.x + threadIdx.x;
    int total = 3 * batch * LATENT;
    if (t >= total) return;
    int d = t & 63;
    int b = t >> 6;
    int g = b / batch;
    int bb = b - g * batch;
    int r = (g == 0) ? users[bb] : (g == 1) ? (N_USERS_C + pos[bb]) : (N_USERS_C + neg[bb]);
    float e0 = E0[r * LATENT + d];
    out[t] = 0.25f * (e0 + acc[t]);
    out[total + t] = e0;
}

extern "C" void kernel_launch(void* const* d_in, const int* in_sizes, int n_in,
                              void* d_out, int out_size, void* d_ws, size_t ws_size,
                              hipStream_t stream) {
    const int*   users = (const int*)d_in[0];
    const int*   pos   = (const int*)d_in[1];
    const int*   neg   = (const int*)d_in[2];
    const float* E0    = (const float*)d_in[3];
    const int*   row   = (const int*)d_in[4];
    const int*   col   = (const int*)d_in[5];
    const float* vals  = (const float*)d_in[6];
    float*       out   = (float*)d_out;

    const int batch  = in_sizes[0];          // 4096
    const int nnz    = in_sizes[4];          // 1,200,000
    const int ntotal = in_sizes[3] / LATENT; // 150,000

    auto align256 = [](size_t x) { return (x + 255) & ~(size_t)255; };

    const size_t bufBytes   = align256((size_t)ntotal * LATENT * sizeof(float)); // 38.4 MB
    const size_t edgeBytes  = align256((size_t)nnz * sizeof(int2));              // 9.6 MB
    const size_t startBytes = align256((size_t)(ntotal + 1) * sizeof(int));
    const size_t curBytes   = align256((size_t)ntotal * sizeof(int));
    const size_t degBytes   = align256((size_t)ntotal * sizeof(int));
    const size_t accBytes   = align256((size_t)3 * batch * LATENT * sizeof(float));

    char* p = (char*)d_ws;
    float* bufA   = (float*)p;              p += bufBytes;
    float* bufB   = (float*)p;              p += bufBytes;
    int2*  edges  = (int2*)p;               p += edgeBytes;
    int*   startA = (int*)p;                p += startBytes;
    int*   cursor = (int*)p;                p += curBytes;
    // deg and acc adjacent so one memset zeroes both:
    int*   deg    = (int*)p;                p += degBytes;
    float* acc    = (float*)p;              p += accBytes;

    hipMemsetAsync(deg, 0, degBytes + accBytes, stream);

    const int threads = 256;
    const int eBlocks = (nnz + threads - 1) / threads;
    const int sBlocks = (ntotal * LATENT + threads - 1) / threads;
    const int gBlocks = (3 * batch * LATENT + threads - 1) / threads;

    // Build CSR (every call; deterministic work, graph-capture safe)
    hist_kernel<<<eBlocks, threads, 0, stream>>>(row, deg, nnz);
    exscan_kernel<<<1, 1024, 0, stream>>>(deg, startA, ntotal);
    hipMemcpyAsync(cursor, startA, (size_t)ntotal * sizeof(int),
                   hipMemcpyDeviceToDevice, stream);
    scatter_kernel<<<eBlocks, threads, 0, stream>>>(row, col, vals, cursor, edges, nnz);

    // Layer 1: E1 = A @ E0 -> bufA
    spmm_csr<<<sBlocks, threads, 0, stream>>>(startA, edges, E0, bufA, ntotal);
    gather_acc<<<gBlocks, threads, 0, stream>>>(users, pos, neg, bufA, acc, batch);
    // Layer 2: E2 = A @ E1 -> bufB
    spmm_csr<<<sBlocks, threads, 0, stream>>>(startA, edges, bufA, bufB, ntotal);
    gather_acc<<<gBlocks, threads, 0, stream>>>(users, pos, neg, bufB, acc, batch);
    // Layer 3: E3 = A @ E2 -> bufA
    spmm_csr<<<sBlocks, threads, 0, stream>>>(startA, edges, bufB, bufA, ntotal);
    gather_acc<<<gBlocks, threads, 0, stream>>>(users, pos, neg, bufA, acc, batch);

    finalize<<<gBlocks, threads, 0, stream>>>(users, pos, neg, E0, acc, out, batch);
}

// Round 3
// 597.698 us; speedup vs baseline: 1.5129x; 1.3986x over previous
//
#include <hip/hip_runtime.h>

#define LATENT 64
#define N_USERS_C 100000

#define SCAN_T 256
#define SCAN_E 4
#define SCAN_CHUNK (SCAN_T * SCAN_E)   // 1024 elements per block

// ---------- CSR build ----------

__global__ void hist_kernel(const int* __restrict__ row, int* __restrict__ deg, int nnz) {
    int e = blockIdx.x * blockDim.x + threadIdx.x;
    if (e >= nnz) return;
    atomicAdd(&deg[row[e]], 1);
}

// Pass 1: per-block local inclusive scan (pre-offset) into start[i+1]; block totals out.
__global__ void scan1_kernel(const int* __restrict__ deg, int* __restrict__ start,
                             int* __restrict__ blockSums, int n) {
    __shared__ int part[SCAN_T];
    int b = blockIdx.x, t = threadIdx.x;
    int base = b * SCAN_CHUNK + t * SCAN_E;
    int v[SCAN_E];
    int s = 0;
#pragma unroll
    for (int j = 0; j < SCAN_E; j++) {
        int i = base + j;
        v[j] = (i < n) ? deg[i] : 0;
        s += v[j];
    }
    part[t] = s;
    __syncthreads();
    for (int off = 1; off < SCAN_T; off <<= 1) {
        int x = (t >= off) ? part[t - off] : 0;
        __syncthreads();
        part[t] += x;
        __syncthreads();
    }
    int run = (t == 0) ? 0 : part[t - 1];
#pragma unroll
    for (int j = 0; j < SCAN_E; j++) {
        int i = base + j;
        run += v[j];
        if (i < n) start[i + 1] = run;   // local inclusive, pre-offset
    }
    if (t == SCAN_T - 1) blockSums[b] = part[SCAN_T - 1];
}

// Pass 2: exclusive scan of block sums (nb <= 256 fits one block).
__global__ void scan2_kernel(int* __restrict__ blockSums, int nb) {
    __shared__ int part[SCAN_T];
    int t = threadIdx.x;
    part[t] = (t < nb) ? blockSums[t] : 0;
    __syncthreads();
    for (int off = 1; off < SCAN_T; off <<= 1) {
        int x = (t >= off) ? part[t - off] : 0;
        __syncthreads();
        part[t] += x;
        __syncthreads();
    }
    if (t < nb) blockSums[t] = (t == 0) ? 0 : part[t - 1];
}

// Pass 3: add block offsets; also emit cursor[i] = start[i] for the scatter.
__global__ void scan3_kernel(const int* __restrict__ deg, int* __restrict__ start,
                             const int* __restrict__ blockOff, int* __restrict__ cursor,
                             int n) {
    int i = blockIdx.x * blockDim.x + threadIdx.x;
    if (i >= n) return;
    int s = start[i + 1] + blockOff[i / SCAN_CHUNK];
    start[i + 1] = s;
    cursor[i] = s - deg[i];
    if (i == 0) start[0] = 0;
}

// Scatter edges into CSR order; cursor pre-initialized to start[0..n).
__global__ void scatter_kernel(const int* __restrict__ row, const int* __restrict__ col,
                               const float* __restrict__ vals, int* __restrict__ cursor,
                               int2* __restrict__ edges, int nnz) {
    int e = blockIdx.x * blockDim.x + threadIdx.x;
    if (e >= nnz) return;
    int r = row[e];
    int p = atomicAdd(&cursor[r], 1);
    edges[p] = make_int2(col[e], __float_as_int(vals[e]));
}

// ---------- Row-parallel SpMM: one wave per row, lane = dim ----------

__global__ void spmm_csr(const int* __restrict__ start, const int2* __restrict__ edges,
                         const float* __restrict__ Ein, float* __restrict__ Eout,
                         int nrows) {
    int t = blockIdx.x * blockDim.x + threadIdx.x;
    int r = t >> 6;
    if (r >= nrows) return;
    int d = t & 63;
    int b = start[r];
    int e = start[r + 1];
    float acc = 0.0f;
    for (int k = b; k < e; k++) {
        int2 ed = edges[k];              // wave-uniform 8B load
        acc += __int_as_float(ed.y) * Ein[ed.x * LATENT + d];  // coalesced 256B gather
    }
    Eout[r * LATENT + d] = acc;
}

// ---------- epilogue ----------

__global__ void gather_acc(const int* __restrict__ users, const int* __restrict__ pos,
                           const int* __restrict__ neg, const float* __restrict__ E,
                           float* __restrict__ acc, int batch) {
    int t = blockIdx.x * blockDim.x + threadIdx.x;
    int total = 3 * batch * LATENT;
    if (t >= total) return;
    int d = t & 63;
    int b = t >> 6;
    int g = b / batch;
    int bb = b - g * batch;
    int r = (g == 0) ? users[bb] : (g == 1) ? (N_USERS_C + pos[bb]) : (N_USERS_C + neg[bb]);
    acc[t] += E[r * LATENT + d];
}

__global__ void finalize(const int* __restrict__ users, const int* __restrict__ pos,
                         const int* __restrict__ neg, const float* __restrict__ E0,
                         const float* __restrict__ acc, float* __restrict__ out, int batch) {
    int t = blockIdx.x * blockDim.x + threadIdx.x;
    int total = 3 * batch * LATENT;
    if (t >= total) return;
    int d = t & 63;
    int b = t >> 6;
    int g = b / batch;
    int bb = b - g * batch;
    int r = (g == 0) ? users[bb] : (g == 1) ? (N_USERS_C + pos[bb]) : (N_USERS_C + neg[bb]);
    float e0 = E0[r * LATENT + d];
    out[t] = 0.25f * (e0 + acc[t]);
    out[total + t] = e0;
}

extern "C" void kernel_launch(void* const* d_in, const int* in_sizes, int n_in,
                              void* d_out, int out_size, void* d_ws, size_t ws_size,
                              hipStream_t stream) {
    const int*   users = (const int*)d_in[0];
    const int*   pos   = (const int*)d_in[1];
    const int*   neg   = (const int*)d_in[2];
    const float* E0    = (const float*)d_in[3];
    const int*   row   = (const int*)d_in[4];
    const int*   col   = (const int*)d_in[5];
    const float* vals  = (const float*)d_in[6];
    float*       out   = (float*)d_out;

    const int batch  = in_sizes[0];          // 4096
    const int nnz    = in_sizes[4];          // 1,200,000
    const int ntotal = in_sizes[3] / LATENT; // 150,000

    auto align256 = [](size_t x) { return (x + 255) & ~(size_t)255; };

    const size_t bufBytes   = align256((size_t)ntotal * LATENT * sizeof(float)); // 38.4 MB
    const size_t edgeBytes  = align256((size_t)nnz * sizeof(int2));              // 9.6 MB
    const size_t startBytes = align256((size_t)(ntotal + 1) * sizeof(int));
    const size_t curBytes   = align256((size_t)ntotal * sizeof(int));
    const size_t degBytes   = align256((size_t)ntotal * sizeof(int));
    const size_t bsBytes    = align256((size_t)SCAN_T * sizeof(int));
    const size_t accBytes   = align256((size_t)3 * batch * LATENT * sizeof(float));

    char* p = (char*)d_ws;
    float* bufA   = (float*)p;              p += bufBytes;
    float* bufB   = (float*)p;              p += bufBytes;
    int2*  edges  = (int2*)p;               p += edgeBytes;
    int*   startA = (int*)p;                p += startBytes;
    int*   cursor = (int*)p;                p += curBytes;
    int*   bsums  = (int*)p;                p += bsBytes;
    // deg and acc adjacent so one memset zeroes both:
    int*   deg    = (int*)p;                p += degBytes;
    float* acc    = (float*)p;              p += accBytes;

    hipMemsetAsync(deg, 0, degBytes + accBytes, stream);

    const int threads = 256;
    const int eBlocks = (nnz + threads - 1) / threads;
    const int sBlocks = (ntotal * LATENT + threads - 1) / threads;
    const int gBlocks = (3 * batch * LATENT + threads - 1) / threads;
    const int scanBlocks = (ntotal + SCAN_CHUNK - 1) / SCAN_CHUNK;   // 147
    const int nBlocks = (ntotal + threads - 1) / threads;

    // Build CSR (multi-block scan; cursor emitted by scan3, no memcpy)
    hist_kernel<<<eBlocks, threads, 0, stream>>>(row, deg, nnz);
    scan1_kernel<<<scanBlocks, SCAN_T, 0, stream>>>(deg, startA, bsums, ntotal);
    scan2_kernel<<<1, SCAN_T, 0, stream>>>(bsums, scanBlocks);
    scan3_kernel<<<nBlocks, threads, 0, stream>>>(deg, startA, bsums, cursor, ntotal);
    scatter_kernel<<<eBlocks, threads, 0, stream>>>(row, col, vals, cursor, edges, nnz);

    // Layer 1: E1 = A @ E0 -> bufA
    spmm_csr<<<sBlocks, threads, 0, stream>>>(startA, edges, E0, bufA, ntotal);
    gather_acc<<<gBlocks, threads, 0, stream>>>(users, pos, neg, bufA, acc, batch);
    // Layer 2: E2 = A @ E1 -> bufB
    spmm_csr<<<sBlocks, threads, 0, stream>>>(startA, edges, bufA, bufB, ntotal);
    gather_acc<<<gBlocks, threads, 0, stream>>>(users, pos, neg, bufB, acc, batch);
    // Layer 3: E3 = A @ E2 -> bufA
    spmm_csr<<<sBlocks, threads, 0, stream>>>(startA, edges, bufB, bufA, ntotal);
    gather_acc<<<gBlocks, threads, 0, stream>>>(users, pos, neg, bufA, acc, batch);

    finalize<<<gBlocks, threads, 0, stream>>>(users, pos, neg, E0, acc, out, batch);
}

// Round 4
// 491.756 us; speedup vs baseline: 1.8388x; 1.2154x over previous
//
#include <hip/hip_runtime.h>

#define LATENT 64
#define N_USERS_C 100000

#define SCAN_T 256
#define SCAN_E 4
#define SCAN_CHUNK (SCAN_T * SCAN_E)   // 1024 elements per block

// ---------- CSR build ----------

__global__ void hist_kernel(const int* __restrict__ row, int* __restrict__ deg, int nnz) {
    int e = blockIdx.x * blockDim.x + threadIdx.x;
    if (e >= nnz) return;
    atomicAdd(&deg[row[e]], 1);
}

// Pass 1: per-block local inclusive scan (pre-offset) into start[i+1]; block totals out.
__global__ void scan1_kernel(const int* __restrict__ deg, int* __restrict__ start,
                             int* __restrict__ blockSums, int n) {
    __shared__ int part[SCAN_T];
    int b = blockIdx.x, t = threadIdx.x;
    int base = b * SCAN_CHUNK + t * SCAN_E;
    int v[SCAN_E];
    int s = 0;
#pragma unroll
    for (int j = 0; j < SCAN_E; j++) {
        int i = base + j;
        v[j] = (i < n) ? deg[i] : 0;
        s += v[j];
    }
    part[t] = s;
    __syncthreads();
    for (int off = 1; off < SCAN_T; off <<= 1) {
        int x = (t >= off) ? part[t - off] : 0;
        __syncthreads();
        part[t] += x;
        __syncthreads();
    }
    int run = (t == 0) ? 0 : part[t - 1];
#pragma unroll
    for (int j = 0; j < SCAN_E; j++) {
        int i = base + j;
        run += v[j];
        if (i < n) start[i + 1] = run;   // local inclusive, pre-offset
    }
    if (t == SCAN_T - 1) blockSums[b] = part[SCAN_T - 1];
}

// Pass 2: exclusive scan of block sums (nb <= 256 fits one block).
__global__ void scan2_kernel(int* __restrict__ blockSums, int nb) {
    __shared__ int part[SCAN_T];
    int t = threadIdx.x;
    part[t] = (t < nb) ? blockSums[t] : 0;
    __syncthreads();
    for (int off = 1; off < SCAN_T; off <<= 1) {
        int x = (t >= off) ? part[t - off] : 0;
        __syncthreads();
        part[t] += x;
        __syncthreads();
    }
    if (t < nb) blockSums[t] = (t == 0) ? 0 : part[t - 1];
}

// Pass 3: add block offsets; also emit cursor[i] = start[i] for the scatter.
__global__ void scan3_kernel(const int* __restrict__ deg, int* __restrict__ start,
                             const int* __restrict__ blockOff, int* __restrict__ cursor,
                             int n) {
    int i = blockIdx.x * blockDim.x + threadIdx.x;
    if (i >= n) return;
    int s = start[i + 1] + blockOff[i / SCAN_CHUNK];
    start[i + 1] = s;
    cursor[i] = s - deg[i];
    if (i == 0) start[0] = 0;
}

// Scatter edges into CSR order; cursor pre-initialized to start[0..n).
__global__ void scatter_kernel(const int* __restrict__ row, const int* __restrict__ col,
                               const float* __restrict__ vals, int* __restrict__ cursor,
                               int2* __restrict__ edges, int nnz) {
    int e = blockIdx.x * blockDim.x + threadIdx.x;
    if (e >= nnz) return;
    int r = row[e];
    int p = atomicAdd(&cursor[r], 1);
    edges[p] = make_int2(col[e], __float_as_int(vals[e]));
}

// ---------- Row-parallel SpMM: one wave per row, lane = dim ----------
// Edge loop chunked by 8, fully unrolled inside with predication so 8
// gathers are in flight per wave (MLP 8) instead of 1. Dummy edges use
// col=0 (valid hot address) with val=0.0 -> contribute exactly +0.0.

__global__ void spmm_csr(const int* __restrict__ start, const int2* __restrict__ edges,
                         const float* __restrict__ Ein, float* __restrict__ Eout,
                         int nrows) {
    int t = blockIdx.x * blockDim.x + threadIdx.x;
    int r = t >> 6;
    if (r >= nrows) return;
    int d = t & 63;
    int b = start[r];
    int e = start[r + 1];
    float acc = 0.0f;
    for (int k = b; k < e; k += 8) {
        int2 ed[8];
#pragma unroll
        for (int j = 0; j < 8; j++) {
            int kk = k + j;
            ed[j] = (kk < e) ? edges[kk] : make_int2(0, 0);
        }
        float g[8];
#pragma unroll
        for (int j = 0; j < 8; j++) {
            g[j] = Ein[ed[j].x * LATENT + d];   // 8 independent gathers in flight
        }
#pragma unroll
        for (int j = 0; j < 8; j++) {
            acc += __int_as_float(ed[j].y) * g[j];
        }
    }
    Eout[r * LATENT + d] = acc;
}

// ---------- epilogue ----------

__global__ void gather_acc(const int* __restrict__ users, const int* __restrict__ pos,
                           const int* __restrict__ neg, const float* __restrict__ E,
                           float* __restrict__ acc, int batch) {
    int t = blockIdx.x * blockDim.x + threadIdx.x;
    int total = 3 * batch * LATENT;
    if (t >= total) return;
    int d = t & 63;
    int b = t >> 6;
    int g = b / batch;
    int bb = b - g * batch;
    int r = (g == 0) ? users[bb] : (g == 1) ? (N_USERS_C + pos[bb]) : (N_USERS_C + neg[bb]);
    acc[t] += E[r * LATENT + d];
}

__global__ void finalize(const int* __restrict__ users, const int* __restrict__ pos,
                         const int* __restrict__ neg, const float* __restrict__ E0,
                         const float* __restrict__ acc, float* __restrict__ out, int batch) {
    int t = blockIdx.x * blockDim.x + threadIdx.x;
    int total = 3 * batch * LATENT;
    if (t >= total) return;
    int d = t & 63;
    int b = t >> 6;
    int g = b / batch;
    int bb = b - g * batch;
    int r = (g == 0) ? users[bb] : (g == 1) ? (N_USERS_C + pos[bb]) : (N_USERS_C + neg[bb]);
    float e0 = E0[r * LATENT + d];
    out[t] = 0.25f * (e0 + acc[t]);
    out[total + t] = e0;
}

extern "C" void kernel_launch(void* const* d_in, const int* in_sizes, int n_in,
                              void* d_out, int out_size, void* d_ws, size_t ws_size,
                              hipStream_t stream) {
    const int*   users = (const int*)d_in[0];
    const int*   pos   = (const int*)d_in[1];
    const int*   neg   = (const int*)d_in[2];
    const float* E0    = (const float*)d_in[3];
    const int*   row   = (const int*)d_in[4];
    const int*   col   = (const int*)d_in[5];
    const float* vals  = (const float*)d_in[6];
    float*       out   = (float*)d_out;

    const int batch  = in_sizes[0];          // 4096
    const int nnz    = in_sizes[4];          // 1,200,000
    const int ntotal = in_sizes[3] / LATENT; // 150,000

    auto align256 = [](size_t x) { return (x + 255) & ~(size_t)255; };

    const size_t bufBytes   = align256((size_t)ntotal * LATENT * sizeof(float)); // 38.4 MB
    const size_t edgeBytes  = align256((size_t)nnz * sizeof(int2));              // 9.6 MB
    const size_t startBytes = align256((size_t)(ntotal + 1) * sizeof(int));
    const size_t curBytes   = align256((size_t)ntotal * sizeof(int));
    const size_t degBytes   = align256((size_t)ntotal * sizeof(int));
    const size_t bsBytes    = align256((size_t)SCAN_T * sizeof(int));
    const size_t accBytes   = align256((size_t)3 * batch * LATENT * sizeof(float));

    char* p = (char*)d_ws;
    float* bufA   = (float*)p;              p += bufBytes;
    float* bufB   = (float*)p;              p += bufBytes;
    int2*  edges  = (int2*)p;               p += edgeBytes;
    int*   startA = (int*)p;                p += startBytes;
    int*   cursor = (int*)p;                p += curBytes;
    int*   bsums  = (int*)p;                p += bsBytes;
    // deg and acc adjacent so one memset zeroes both:
    int*   deg    = (int*)p;                p += degBytes;
    float* acc    = (float*)p;              p += accBytes;

    hipMemsetAsync(deg, 0, degBytes + accBytes, stream);

    const int threads = 256;
    const int eBlocks = (nnz + threads - 1) / threads;
    const int sBlocks = (ntotal * LATENT + threads - 1) / threads;
    const int gBlocks = (3 * batch * LATENT + threads - 1) / threads;
    const int scanBlocks = (ntotal + SCAN_CHUNK - 1) / SCAN_CHUNK;   // 147
    const int nBlocks = (ntotal + threads - 1) / threads;

    // Build CSR (multi-block scan; cursor emitted by scan3, no memcpy)
    hist_kernel<<<eBlocks, threads, 0, stream>>>(row, deg, nnz);
    scan1_kernel<<<scanBlocks, SCAN_T, 0, stream>>>(deg, startA, bsums, ntotal);
    scan2_kernel<<<1, SCAN_T, 0, stream>>>(bsums, scanBlocks);
    scan3_kernel<<<nBlocks, threads, 0, stream>>>(deg, startA, bsums, cursor, ntotal);
    scatter_kernel<<<eBlocks, threads, 0, stream>>>(row, col, vals, cursor, edges, nnz);

    // Layer 1: E1 = A @ E0 -> bufA
    spmm_csr<<<sBlocks, threads, 0, stream>>>(startA, edges, E0, bufA, ntotal);
    gather_acc<<<gBlocks, threads, 0, stream>>>(users, pos, neg, bufA, acc, batch);
    // Layer 2: E2 = A @ E1 -> bufB
    spmm_csr<<<sBlocks, threads, 0, stream>>>(startA, edges, bufA, bufB, ntotal);
    gather_acc<<<gBlocks, threads, 0, stream>>>(users, pos, neg, bufB, acc, batch);
    // Layer 3: E3 = A @ E2 -> bufA
    spmm_csr<<<sBlocks, threads, 0, stream>>>(startA, edges, bufB, bufA, ntotal);
    gather_acc<<<gBlocks, threads, 0, stream>>>(users, pos, neg, bufA, acc, batch);

    finalize<<<gBlocks, threads, 0, stream>>>(users, pos, neg, E0, acc, out, batch);
}